// Round 6
// baseline (373.421 us; speedup 1.0000x reference)
//
#include <hip/hip_runtime.h>

// GCN: N=100000 nodes, E=1600000 edges, dims 128 -> 64 -> 32.
// CSR-by-destination built per launch via bucketed counting sort (LDS-staged,
// no sub-line global scatters). Gather-based aggregation, no feature atomics.
//   pass1: partition (col,row) pairs into 782 buckets of 128 dest nodes.
//   bktscan: scan bucket sizes -> CSR bucket bases.
//   pass2: per-bucket LDS CSR build -> ptr, dinv, adj (coalesced writes only).
//   gemm1: g1 = dinv*(x@W1), register-tiled 16 nodes/wave, W1 direct (L1/L2-hot).
//   agg1g2: h1 = relu(dinv*(self+sum_nbr)g1+b1) in LDS; g2 = dinv*(h1@W2).
//   agg2:   out = dinv*(self+sum_nbr)g2 + b2.

#define NNODES 100000
#define NEDGES 1600000
#define IN_DIM 128
#define HID 64
#define OUTD 32

#define BKT_NODES 128
#define NBUK 782                        // ceil(100000/128)
#define BKT_CAP 3584                    // slots/bucket; mean load 2048
#define P1_BLOCKS 256
#define P1_CHUNK (NEDGES / P1_BLOCKS)   // 6250 exactly

// ---- CSR build ----

__global__ __launch_bounds__(256) void k_pass1(const int* __restrict__ row,
                                               const int* __restrict__ col,
                                               int* __restrict__ gcur,
                                               int2* __restrict__ pairbuf) {
    __shared__ int lcnt[NBUK];
    __shared__ int lbase[NBUK];
    int t = threadIdx.x;
    int e0 = blockIdx.x * P1_CHUNK;
    int e1 = e0 + P1_CHUNK;
    for (int j = t; j < NBUK; j += 256) lcnt[j] = 0;
    __syncthreads();
    for (int e = e0 + t; e < e1; e += 256)
        atomicAdd(&lcnt[col[e] >> 7], 1);
    __syncthreads();
    for (int j = t; j < NBUK; j += 256) {
        int n = lcnt[j];
        lbase[j] = (n > 0) ? atomicAdd(&gcur[j], n) : 0;
    }
    __syncthreads();
    for (int j = t; j < NBUK; j += 256) lcnt[j] = 0;
    __syncthreads();
    for (int e = e0 + t; e < e1; e += 256) {
        int c = col[e];
        int r = row[e];
        int b = c >> 7;
        int pos = lbase[b] + atomicAdd(&lcnt[b], 1);
        if (pos < BKT_CAP) pairbuf[(size_t)b * BKT_CAP + pos] = make_int2(c, r);
    }
}

__global__ __launch_bounds__(1024) void k_bktscan(const int* __restrict__ gcur,
                                                  int* __restrict__ bktbase,
                                                  int* __restrict__ ptr) {
    __shared__ int s[1024];
    int t = threadIdx.x;
    int v = (t < NBUK) ? gcur[t] : 0;
    s[t] = v;
    __syncthreads();
    for (int off = 1; off < 1024; off <<= 1) {
        int u = (t >= off) ? s[t - off] : 0;
        __syncthreads();
        s[t] += u;
        __syncthreads();
    }
    if (t < NBUK) bktbase[t] = s[t] - v;  // exclusive
    if (t == 0) { bktbase[NBUK] = NEDGES; ptr[NNODES] = NEDGES; }
}

__global__ __launch_bounds__(256) void k_pass2(const int2* __restrict__ pairbuf,
                                               const int* __restrict__ gcur,
                                               const int* __restrict__ bktbase,
                                               int* __restrict__ ptr,
                                               float* __restrict__ dinv,
                                               int* __restrict__ adj) {
    __shared__ int ncnt[BKT_NODES];
    __shared__ int nsc[BKT_NODES];
    __shared__ int ncur[BKT_NODES];
    __shared__ int seg[BKT_CAP];
    int b = blockIdx.x;
    int t = threadIdx.x;
    int c0 = b * BKT_NODES;
    int nb = NNODES - c0; if (nb > BKT_NODES) nb = BKT_NODES;
    int size = gcur[b]; if (size > BKT_CAP) size = BKT_CAP;
    int base = bktbase[b];
    const int2* pp = pairbuf + (size_t)b * BKT_CAP;

    if (t < BKT_NODES) ncnt[t] = 0;
    __syncthreads();
    for (int k = t; k < size; k += 256)
        atomicAdd(&ncnt[pp[k].x - c0], 1);
    __syncthreads();
    int myv = (t < BKT_NODES) ? ncnt[t] : 0;
    if (t < BKT_NODES) nsc[t] = myv;
    __syncthreads();
    for (int off = 1; off < BKT_NODES; off <<= 1) {
        int u = 0;
        if (t < BKT_NODES && t >= off) u = nsc[t - off];
        __syncthreads();
        if (t < BKT_NODES) nsc[t] += u;
        __syncthreads();
    }
    if (t < BKT_NODES) {
        int excl = nsc[t] - myv;
        ncur[t] = excl;
        if (t < nb) {
            ptr[c0 + t] = base + excl;
            dinv[c0 + t] = rsqrtf((float)myv + 1.0f);  // +1 self-loop
        }
    }
    __syncthreads();
    for (int k = t; k < size; k += 256) {
        int2 pr = pp[k];
        int pos = atomicAdd(&ncur[pr.x - c0], 1);
        seg[pos] = pr.y;  // LDS scatter (cheap), global stays coalesced
    }
    __syncthreads();
    for (int k = t; k < size; k += 256) adj[base + k] = seg[k];
}

// ---- layer kernels ----

// g1 = dinv * (x @ W1); each wave computes 16 nodes, lane = hidden j.
// No LDS, no barrier: W1 (32KB) read direct, coalesced, L1/L2-hot.
// Per 4-k chunk: 16 uniform float4 x-loads + 4 coalesced W loads + 64 FMA.
#define NT 16
__global__ __launch_bounds__(256) void k_gemm1(const float* __restrict__ x,
                                               const float* __restrict__ W1,
                                               const float* __restrict__ dinv,
                                               float* __restrict__ g1) {
    int wid = (blockIdx.x * blockDim.x + threadIdx.x) >> 6;
    int lane = threadIdx.x & 63;
    int base = wid * NT;
    if (base >= NNODES) return;

    const float4* xq = reinterpret_cast<const float4*>(x + (size_t)base * IN_DIM);
    // node n's row = xq[n*32 + kc], kc in [0,32)

    float acc[NT];
#pragma unroll
    for (int n = 0; n < NT; ++n) acc[n] = 0.0f;

    for (int kc = 0; kc < IN_DIM / 4; ++kc) {
        float4 xv[NT];
#pragma unroll
        for (int n = 0; n < NT; ++n) xv[n] = xq[n * 32 + kc];  // 16 independent 16B loads
        float w0 = W1[(kc * 4 + 0) * HID + lane];  // coalesced 256B, L1/L2-hot
        float w1 = W1[(kc * 4 + 1) * HID + lane];
        float w2 = W1[(kc * 4 + 2) * HID + lane];
        float w3 = W1[(kc * 4 + 3) * HID + lane];
#pragma unroll
        for (int n = 0; n < NT; ++n) {
            acc[n] = fmaf(xv[n].x, w0, acc[n]);
            acc[n] = fmaf(xv[n].y, w1, acc[n]);
            acc[n] = fmaf(xv[n].z, w2, acc[n]);
            acc[n] = fmaf(xv[n].w, w3, acc[n]);
        }
    }
#pragma unroll
    for (int n = 0; n < NT; ++n)
        g1[(size_t)(base + n) * HID + lane] = dinv[base + n] * acc[n];
}

// fused: h1 = relu(dinv*(g1[i]+sum_nbr g1)+b1) in LDS; g2 = dinv*(h1@W2).
// one wave per node; neighbor loop unrolled x8.
__global__ __launch_bounds__(256) void k_agg1g2(const float* __restrict__ g1,
                                                const int* __restrict__ ptr,
                                                const int* __restrict__ adj,
                                                const float* __restrict__ dinv,
                                                const float* __restrict__ b1,
                                                const float* __restrict__ W2,
                                                float* __restrict__ g2) {
    __shared__ float sh[4][HID];
    int t = blockIdx.x * blockDim.x + threadIdx.x;
    int i = t >> 6;
    if (i >= NNODES) return;
    int lane = threadIdx.x & 63;
    int w = threadIdx.x >> 6;

    float s = g1[(size_t)i * HID + lane];  // self loop
    int p0 = ptr[i], p1 = ptr[i + 1];
    int p = p0;
    for (; p + 8 <= p1; p += 8) {
        int n0 = adj[p],     n1 = adj[p + 1], n2 = adj[p + 2], n3 = adj[p + 3];
        int n4 = adj[p + 4], n5 = adj[p + 5], n6 = adj[p + 6], n7 = adj[p + 7];
        float v0 = g1[(size_t)n0 * HID + lane];
        float v1 = g1[(size_t)n1 * HID + lane];
        float v2 = g1[(size_t)n2 * HID + lane];
        float v3 = g1[(size_t)n3 * HID + lane];
        float v4 = g1[(size_t)n4 * HID + lane];
        float v5 = g1[(size_t)n5 * HID + lane];
        float v6 = g1[(size_t)n6 * HID + lane];
        float v7 = g1[(size_t)n7 * HID + lane];
        s += ((v0 + v1) + (v2 + v3)) + ((v4 + v5) + (v6 + v7));
    }
    for (; p < p1; ++p) s += g1[(size_t)adj[p] * HID + lane];

    float di = dinv[i];
    float h = fmaxf(fmaf(di, s, b1[lane]), 0.0f);
    sh[w][lane] = h;  // wave-synchronous, no barrier needed

    int j2 = lane & 31;
    int half = lane >> 5;
    float acc = 0.0f;
#pragma unroll
    for (int j = 0; j < 32; ++j) {
        int jj = half * 32 + j;
        acc = fmaf(sh[w][jj], W2[jj * OUTD + j2], acc);
    }
    acc += __shfl_xor(acc, 32);
    if (half == 0) g2[(size_t)i * OUTD + j2] = di * acc;
}

// out = dinv * (g2[i] + sum_nbr g2[nbr]) + b2; half-wave per node, unrolled x8.
__global__ void k_agg2(const float* __restrict__ g2, const int* __restrict__ ptr,
                       const int* __restrict__ adj, const float* __restrict__ dinv,
                       const float* __restrict__ b2, float* __restrict__ out) {
    int t = blockIdx.x * blockDim.x + threadIdx.x;
    int i = t >> 5;
    int j = t & 31;
    if (i >= NNODES) return;
    float s = g2[(size_t)i * OUTD + j];  // self loop
    int p0 = ptr[i], p1 = ptr[i + 1];
    int p = p0;
    for (; p + 8 <= p1; p += 8) {
        int n0 = adj[p],     n1 = adj[p + 1], n2 = adj[p + 2], n3 = adj[p + 3];
        int n4 = adj[p + 4], n5 = adj[p + 5], n6 = adj[p + 6], n7 = adj[p + 7];
        float v0 = g2[(size_t)n0 * OUTD + j];
        float v1 = g2[(size_t)n1 * OUTD + j];
        float v2 = g2[(size_t)n2 * OUTD + j];
        float v3 = g2[(size_t)n3 * OUTD + j];
        float v4 = g2[(size_t)n4 * OUTD + j];
        float v5 = g2[(size_t)n5 * OUTD + j];
        float v6 = g2[(size_t)n6 * OUTD + j];
        float v7 = g2[(size_t)n7 * OUTD + j];
        s += ((v0 + v1) + (v2 + v3)) + ((v4 + v5) + (v6 + v7));
    }
    for (; p < p1; ++p) s += g2[(size_t)adj[p] * OUTD + j];
    out[(size_t)i * OUTD + j] = fmaf(dinv[i], s, b2[j]);
}

extern "C" void kernel_launch(void* const* d_in, const int* in_sizes, int n_in,
                              void* d_out, int out_size, void* d_ws, size_t ws_size,
                              hipStream_t stream) {
    const float* x  = (const float*)d_in[0];
    const int*   ei = (const int*)d_in[1];   // [2, E]
    const float* W1 = (const float*)d_in[2];
    const float* b1 = (const float*)d_in[3];
    const float* W2 = (const float*)d_in[4];
    const float* b2 = (const float*)d_in[5];
    float* out = (float*)d_out;

    const int* row = ei;            // source
    const int* col = ei + NEDGES;   // target

    char* ws = (char*)d_ws;
    size_t off = 0;
    auto alloc = [&](size_t bytes) {
        void* p = ws + off;
        off = (off + bytes + 511) & ~(size_t)511;
        return p;
    };
    int*   gcur    = (int*)  alloc((size_t)NBUK * 4);
    int*   bktbase = (int*)  alloc((size_t)(NBUK + 1) * 4);
    int*   ptr     = (int*)  alloc((size_t)(NNODES + 1) * 4);
    float* dinv    = (float*)alloc((size_t)NNODES * 4);
    int*   adj     = (int*)  alloc((size_t)NEDGES * 4);
    float* g2      = (float*)alloc((size_t)NNODES * OUTD * 4);
    // pairbuf (22.4MB) and g1 (25.6MB) share one region: pairbuf dead after k_pass2.
    size_t big = (size_t)NBUK * BKT_CAP * 8;
    size_t g1b = (size_t)NNODES * HID * 4;
    int2*  pairbuf = (int2*) alloc(big > g1b ? big : g1b);
    float* g1      = (float*)pairbuf;

    const int B = 256;
    hipMemsetAsync(gcur, 0, (size_t)NBUK * 4, stream);
    k_pass1<<<P1_BLOCKS, 256, 0, stream>>>(row, col, gcur, pairbuf);
    k_bktscan<<<1, 1024, 0, stream>>>(gcur, bktbase, ptr);
    k_pass2<<<NBUK, 256, 0, stream>>>(pairbuf, gcur, bktbase, ptr, dinv, adj);

    {
        // 16 nodes per wave: 6250 waves = 400000 threads
        long long tot = (long long)(NNODES / NT) * 64;
        k_gemm1<<<(int)((tot + B - 1) / B), B, 0, stream>>>(x, W1, dinv, g1);
    }
    {
        long long tot = (long long)NNODES * HID;
        k_agg1g2<<<(int)((tot + B - 1) / B), B, 0, stream>>>(g1, ptr, adj, dinv, b1, W2, g2);
    }
    {
        long long tot = (long long)NNODES * OUTD;
        k_agg2<<<(int)((tot + B - 1) / B), B, 0, stream>>>(g2, ptr, adj, dinv, b2, out);
    }
}

// Round 8
// 301.215 us; speedup vs baseline: 1.2397x; 1.2397x over previous
//
#include <hip/hip_runtime.h>

// GCN: N=100000 nodes, E=1600000 edges, dims 128 -> 64 -> 32.
// CSR-by-destination built per launch via bucketed counting sort (LDS-staged,
// no sub-line global scatters). Gather-based aggregation, no feature atomics.
//   pass1: partition (col,row) pairs into 782 buckets of 128 dest nodes.
//   bktscan: scan bucket sizes -> CSR bucket bases.
//   pass2: per-bucket LDS CSR build -> ptr, dinv, adj (coalesced writes only).
//   gemm1: g1 = dinv*(x@W1); 64-node tile staged in LDS (coalesced), compute
//          reads x via wave-uniform ds_read_b128 (120cy, not 900cy HBM).
//   agg1g2: h1 = relu(dinv*(self+sum_nbr)g1+b1) in LDS; g2 = dinv*(h1@W2).
//   agg2:   out = dinv*(self+sum_nbr)g2 + b2.

#define NNODES 100000
#define NEDGES 1600000
#define IN_DIM 128
#define HID 64
#define OUTD 32

#define BKT_NODES 128
#define NBUK 782                        // ceil(100000/128)
#define BKT_CAP 3584                    // slots/bucket; mean load 2048
#define P1_BLOCKS 256
#define P1_CHUNK (NEDGES / P1_BLOCKS)   // 6250 exactly

// ---- CSR build ----

__global__ __launch_bounds__(256) void k_pass1(const int* __restrict__ row,
                                               const int* __restrict__ col,
                                               int* __restrict__ gcur,
                                               int2* __restrict__ pairbuf) {
    __shared__ int lcnt[NBUK];
    __shared__ int lbase[NBUK];
    int t = threadIdx.x;
    int e0 = blockIdx.x * P1_CHUNK;
    int e1 = e0 + P1_CHUNK;
    for (int j = t; j < NBUK; j += 256) lcnt[j] = 0;
    __syncthreads();
    for (int e = e0 + t; e < e1; e += 256)
        atomicAdd(&lcnt[col[e] >> 7], 1);
    __syncthreads();
    for (int j = t; j < NBUK; j += 256) {
        int n = lcnt[j];
        lbase[j] = (n > 0) ? atomicAdd(&gcur[j], n) : 0;
    }
    __syncthreads();
    for (int j = t; j < NBUK; j += 256) lcnt[j] = 0;
    __syncthreads();
    for (int e = e0 + t; e < e1; e += 256) {
        int c = col[e];
        int r = row[e];
        int b = c >> 7;
        int pos = lbase[b] + atomicAdd(&lcnt[b], 1);
        if (pos < BKT_CAP) pairbuf[(size_t)b * BKT_CAP + pos] = make_int2(c, r);
    }
}

__global__ __launch_bounds__(1024) void k_bktscan(const int* __restrict__ gcur,
                                                  int* __restrict__ bktbase,
                                                  int* __restrict__ ptr) {
    __shared__ int s[1024];
    int t = threadIdx.x;
    int v = (t < NBUK) ? gcur[t] : 0;
    s[t] = v;
    __syncthreads();
    for (int off = 1; off < 1024; off <<= 1) {
        int u = (t >= off) ? s[t - off] : 0;
        __syncthreads();
        s[t] += u;
        __syncthreads();
    }
    if (t < NBUK) bktbase[t] = s[t] - v;  // exclusive
    if (t == 0) { bktbase[NBUK] = NEDGES; ptr[NNODES] = NEDGES; }
}

__global__ __launch_bounds__(256) void k_pass2(const int2* __restrict__ pairbuf,
                                               const int* __restrict__ gcur,
                                               const int* __restrict__ bktbase,
                                               int* __restrict__ ptr,
                                               float* __restrict__ dinv,
                                               int* __restrict__ adj) {
    __shared__ int ncnt[BKT_NODES];
    __shared__ int nsc[BKT_NODES];
    __shared__ int ncur[BKT_NODES];
    __shared__ int seg[BKT_CAP];
    int b = blockIdx.x;
    int t = threadIdx.x;
    int c0 = b * BKT_NODES;
    int nb = NNODES - c0; if (nb > BKT_NODES) nb = BKT_NODES;
    int size = gcur[b]; if (size > BKT_CAP) size = BKT_CAP;
    int base = bktbase[b];
    const int2* pp = pairbuf + (size_t)b * BKT_CAP;

    if (t < BKT_NODES) ncnt[t] = 0;
    __syncthreads();
    for (int k = t; k < size; k += 256)
        atomicAdd(&ncnt[pp[k].x - c0], 1);
    __syncthreads();
    int myv = (t < BKT_NODES) ? ncnt[t] : 0;
    if (t < BKT_NODES) nsc[t] = myv;
    __syncthreads();
    for (int off = 1; off < BKT_NODES; off <<= 1) {
        int u = 0;
        if (t < BKT_NODES && t >= off) u = nsc[t - off];
        __syncthreads();
        if (t < BKT_NODES) nsc[t] += u;
        __syncthreads();
    }
    if (t < BKT_NODES) {
        int excl = nsc[t] - myv;
        ncur[t] = excl;
        if (t < nb) {
            ptr[c0 + t] = base + excl;
            dinv[c0 + t] = rsqrtf((float)myv + 1.0f);  // +1 self-loop
        }
    }
    __syncthreads();
    for (int k = t; k < size; k += 256) {
        int2 pr = pp[k];
        int pos = atomicAdd(&ncur[pr.x - c0], 1);
        seg[pos] = pr.y;  // LDS scatter (cheap), global stays coalesced
    }
    __syncthreads();
    for (int k = t; k < size; k += 256) adj[base + k] = seg[k];
}

// ---- layer kernels ----

// g1 = dinv * (x @ W1).
// Block = 256 thr / 4 waves; 64-node x-tile staged in LDS via coalesced float4.
// Wave w computes nodes [w*16, w*16+16), lane = hidden j.
// Per 4-k chunk: 4 coalesced W1 loads (L1-hot) + 16 uniform ds_read_b128 + 64 FMA.
#define TILE 64
#define NT 16
__global__ __launch_bounds__(256) void k_gemm1(const float* __restrict__ x,
                                               const float* __restrict__ W1,
                                               const float* __restrict__ dinv,
                                               float* __restrict__ g1) {
    __shared__ float shx[TILE][IN_DIM];  // 32 KB
    int t = threadIdx.x;
    int nbase = blockIdx.x * TILE;

    // stage 64 node rows = 2048 float4, 8 per thread, fully coalesced
    const float4* xg = reinterpret_cast<const float4*>(x + (size_t)nbase * IN_DIM);
    float4* shx4 = reinterpret_cast<float4*>(&shx[0][0]);
    int lim = (NNODES - nbase) * (IN_DIM / 4);  // guard for last partial tile
    if (lim > TILE * (IN_DIM / 4)) lim = TILE * (IN_DIM / 4);
#pragma unroll
    for (int it = 0; it < 8; ++it) {
        int idx = t + it * 256;
        if (idx < lim) shx4[idx] = xg[idx];
    }
    __syncthreads();

    int w = t >> 6;
    int lane = t & 63;
    int n0 = w * NT;

    float acc[NT];
#pragma unroll
    for (int n = 0; n < NT; ++n) acc[n] = 0.0f;

    for (int kc = 0; kc < IN_DIM / 4; ++kc) {
        float w0 = W1[(kc * 4 + 0) * HID + lane];  // coalesced 256B, L1-hot
        float w1 = W1[(kc * 4 + 1) * HID + lane];
        float w2 = W1[(kc * 4 + 2) * HID + lane];
        float w3 = W1[(kc * 4 + 3) * HID + lane];
#pragma unroll
        for (int n = 0; n < NT; ++n) {
            float4 xv = *reinterpret_cast<const float4*>(&shx[n0 + n][kc * 4]);
            acc[n] = fmaf(xv.x, w0, acc[n]);
            acc[n] = fmaf(xv.y, w1, acc[n]);
            acc[n] = fmaf(xv.z, w2, acc[n]);
            acc[n] = fmaf(xv.w, w3, acc[n]);
        }
    }
#pragma unroll
    for (int n = 0; n < NT; ++n) {
        int node = nbase + n0 + n;
        if (node < NNODES)
            g1[(size_t)node * HID + lane] = dinv[node] * acc[n];
    }
}

// fused: h1 = relu(dinv*(g1[i]+sum_nbr g1)+b1) in LDS; g2 = dinv*(h1@W2).
// one wave per node; neighbor loop unrolled x8.
__global__ __launch_bounds__(256) void k_agg1g2(const float* __restrict__ g1,
                                                const int* __restrict__ ptr,
                                                const int* __restrict__ adj,
                                                const float* __restrict__ dinv,
                                                const float* __restrict__ b1,
                                                const float* __restrict__ W2,
                                                float* __restrict__ g2) {
    __shared__ float sh[4][HID];
    int t = blockIdx.x * blockDim.x + threadIdx.x;
    int i = t >> 6;
    if (i >= NNODES) return;
    int lane = threadIdx.x & 63;
    int w = threadIdx.x >> 6;

    float s = g1[(size_t)i * HID + lane];  // self loop
    int p0 = ptr[i], p1 = ptr[i + 1];
    int p = p0;
    for (; p + 8 <= p1; p += 8) {
        int n0 = adj[p],     n1 = adj[p + 1], n2 = adj[p + 2], n3 = adj[p + 3];
        int n4 = adj[p + 4], n5 = adj[p + 5], n6 = adj[p + 6], n7 = adj[p + 7];
        float v0 = g1[(size_t)n0 * HID + lane];
        float v1 = g1[(size_t)n1 * HID + lane];
        float v2 = g1[(size_t)n2 * HID + lane];
        float v3 = g1[(size_t)n3 * HID + lane];
        float v4 = g1[(size_t)n4 * HID + lane];
        float v5 = g1[(size_t)n5 * HID + lane];
        float v6 = g1[(size_t)n6 * HID + lane];
        float v7 = g1[(size_t)n7 * HID + lane];
        s += ((v0 + v1) + (v2 + v3)) + ((v4 + v5) + (v6 + v7));
    }
    for (; p < p1; ++p) s += g1[(size_t)adj[p] * HID + lane];

    float di = dinv[i];
    float h = fmaxf(fmaf(di, s, b1[lane]), 0.0f);
    sh[w][lane] = h;  // wave-synchronous, no barrier needed

    int j2 = lane & 31;
    int half = lane >> 5;
    float acc = 0.0f;
#pragma unroll
    for (int j = 0; j < 32; ++j) {
        int jj = half * 32 + j;
        acc = fmaf(sh[w][jj], W2[jj * OUTD + j2], acc);
    }
    acc += __shfl_xor(acc, 32);
    if (half == 0) g2[(size_t)i * OUTD + j2] = di * acc;
}

// out = dinv * (g2[i] + sum_nbr g2[nbr]) + b2; half-wave per node, unrolled x8.
__global__ void k_agg2(const float* __restrict__ g2, const int* __restrict__ ptr,
                       const int* __restrict__ adj, const float* __restrict__ dinv,
                       const float* __restrict__ b2, float* __restrict__ out) {
    int t = blockIdx.x * blockDim.x + threadIdx.x;
    int i = t >> 5;
    int j = t & 31;
    if (i >= NNODES) return;
    float s = g2[(size_t)i * OUTD + j];  // self loop
    int p0 = ptr[i], p1 = ptr[i + 1];
    int p = p0;
    for (; p + 8 <= p1; p += 8) {
        int n0 = adj[p],     n1 = adj[p + 1], n2 = adj[p + 2], n3 = adj[p + 3];
        int n4 = adj[p + 4], n5 = adj[p + 5], n6 = adj[p + 6], n7 = adj[p + 7];
        float v0 = g2[(size_t)n0 * OUTD + j];
        float v1 = g2[(size_t)n1 * OUTD + j];
        float v2 = g2[(size_t)n2 * OUTD + j];
        float v3 = g2[(size_t)n3 * OUTD + j];
        float v4 = g2[(size_t)n4 * OUTD + j];
        float v5 = g2[(size_t)n5 * OUTD + j];
        float v6 = g2[(size_t)n6 * OUTD + j];
        float v7 = g2[(size_t)n7 * OUTD + j];
        s += ((v0 + v1) + (v2 + v3)) + ((v4 + v5) + (v6 + v7));
    }
    for (; p < p1; ++p) s += g2[(size_t)adj[p] * OUTD + j];
    out[(size_t)i * OUTD + j] = fmaf(dinv[i], s, b2[j]);
}

extern "C" void kernel_launch(void* const* d_in, const int* in_sizes, int n_in,
                              void* d_out, int out_size, void* d_ws, size_t ws_size,
                              hipStream_t stream) {
    const float* x  = (const float*)d_in[0];
    const int*   ei = (const int*)d_in[1];   // [2, E]
    const float* W1 = (const float*)d_in[2];
    const float* b1 = (const float*)d_in[3];
    const float* W2 = (const float*)d_in[4];
    const float* b2 = (const float*)d_in[5];
    float* out = (float*)d_out;

    const int* row = ei;            // source
    const int* col = ei + NEDGES;   // target

    char* ws = (char*)d_ws;
    size_t off = 0;
    auto alloc = [&](size_t bytes) {
        void* p = ws + off;
        off = (off + bytes + 511) & ~(size_t)511;
        return p;
    };
    int*   gcur    = (int*)  alloc((size_t)NBUK * 4);
    int*   bktbase = (int*)  alloc((size_t)(NBUK + 1) * 4);
    int*   ptr     = (int*)  alloc((size_t)(NNODES + 1) * 4);
    float* dinv    = (float*)alloc((size_t)NNODES * 4);
    int*   adj     = (int*)  alloc((size_t)NEDGES * 4);
    float* g2      = (float*)alloc((size_t)NNODES * OUTD * 4);
    // pairbuf (22.4MB) and g1 (25.6MB) share one region: pairbuf dead after k_pass2.
    size_t big = (size_t)NBUK * BKT_CAP * 8;
    size_t g1b = (size_t)NNODES * HID * 4;
    int2*  pairbuf = (int2*) alloc(big > g1b ? big : g1b);
    float* g1      = (float*)pairbuf;

    const int B = 256;
    hipMemsetAsync(gcur, 0, (size_t)NBUK * 4, stream);
    k_pass1<<<P1_BLOCKS, 256, 0, stream>>>(row, col, gcur, pairbuf);
    k_bktscan<<<1, 1024, 0, stream>>>(gcur, bktbase, ptr);
    k_pass2<<<NBUK, 256, 0, stream>>>(pairbuf, gcur, bktbase, ptr, dinv, adj);

    {
        int nblk = (NNODES + TILE - 1) / TILE;  // 1563
        k_gemm1<<<nblk, 256, 0, stream>>>(x, W1, dinv, g1);
    }
    {
        long long tot = (long long)NNODES * HID;
        k_agg1g2<<<(int)((tot + B - 1) / B), B, 0, stream>>>(g1, ptr, adj, dinv, b1, W2, g2);
    }
    {
        long long tot = (long long)NNODES * OUTD;
        k_agg2<<<(int)((tot + B - 1) / B), B, 0, stream>>>(g2, ptr, adj, dinv, b2, out);
    }
}

// Round 9
// 300.564 us; speedup vs baseline: 1.2424x; 1.0022x over previous
//
#include <hip/hip_runtime.h>
#include <hip/hip_fp16.h>

// GCN: N=100000 nodes, E=1600000 edges, dims 128 -> 64 -> 32.
// CSR-by-destination built per launch via bucketed counting sort (LDS-staged).
// Gather-based aggregation; g1/g2 stored fp16 to halve gather bytes (accum fp32).
//   pass1: partition packed (r<<7|c&127) edges into 782 buckets of 128 dest nodes.
//   bktscan: scan bucket sizes -> CSR bucket bases.
//   pass2: per-bucket LDS CSR build -> ptr, dinv, adj (coalesced writes only).
//   gemm1: g1 = fp16(dinv*(x@W1)); 64-node x-tile in LDS, W1 direct L1-hot.
//   agg1g2: h1 = relu(dinv*(self+sum_nbr)g1+b1) in LDS; g2 = fp16(dinv*(h1@W2)).
//   agg2:   out = dinv*(self+sum_nbr)g2 + b2 (fp32 out).

#define NNODES 100000
#define NEDGES 1600000
#define IN_DIM 128
#define HID 64
#define OUTD 32

#define BKT_NODES 128
#define NBUK 782                        // ceil(100000/128)
#define BKT_CAP 3584                    // slots/bucket; mean load 2048
#define P1_BLOCKS 256
#define P1_CHUNK (NEDGES / P1_BLOCKS)   // 6250 exactly

// ---- CSR build ----

__global__ __launch_bounds__(256) void k_pass1(const int* __restrict__ row,
                                               const int* __restrict__ col,
                                               int* __restrict__ gcur,
                                               unsigned int* __restrict__ pairbuf) {
    __shared__ int lcnt[NBUK];
    __shared__ int lbase[NBUK];
    int t = threadIdx.x;
    int e0 = blockIdx.x * P1_CHUNK;
    int e1 = e0 + P1_CHUNK;
    for (int j = t; j < NBUK; j += 256) lcnt[j] = 0;
    __syncthreads();
    for (int e = e0 + t; e < e1; e += 256)
        atomicAdd(&lcnt[col[e] >> 7], 1);
    __syncthreads();
    for (int j = t; j < NBUK; j += 256) {
        int n = lcnt[j];
        lbase[j] = (n > 0) ? atomicAdd(&gcur[j], n) : 0;
    }
    __syncthreads();
    for (int j = t; j < NBUK; j += 256) lcnt[j] = 0;
    __syncthreads();
    for (int e = e0 + t; e < e1; e += 256) {
        int c = col[e];
        unsigned int pk = ((unsigned int)row[e] << 7) | (unsigned int)(c & 127);
        int b = c >> 7;
        int pos = lbase[b] + atomicAdd(&lcnt[b], 1);
        if (pos < BKT_CAP) pairbuf[(size_t)b * BKT_CAP + pos] = pk;
    }
}

__global__ __launch_bounds__(1024) void k_bktscan(const int* __restrict__ gcur,
                                                  int* __restrict__ bktbase,
                                                  int* __restrict__ ptr) {
    __shared__ int s[1024];
    int t = threadIdx.x;
    int v = (t < NBUK) ? gcur[t] : 0;
    s[t] = v;
    __syncthreads();
    for (int off = 1; off < 1024; off <<= 1) {
        int u = (t >= off) ? s[t - off] : 0;
        __syncthreads();
        s[t] += u;
        __syncthreads();
    }
    if (t < NBUK) bktbase[t] = s[t] - v;  // exclusive
    if (t == 0) { bktbase[NBUK] = NEDGES; ptr[NNODES] = NEDGES; }
}

__global__ __launch_bounds__(256) void k_pass2(const unsigned int* __restrict__ pairbuf,
                                               const int* __restrict__ gcur,
                                               const int* __restrict__ bktbase,
                                               int* __restrict__ ptr,
                                               float* __restrict__ dinv,
                                               int* __restrict__ adj) {
    __shared__ int ncnt[BKT_NODES];
    __shared__ int nsc[BKT_NODES];
    __shared__ int ncur[BKT_NODES];
    __shared__ int seg[BKT_CAP];
    int b = blockIdx.x;
    int t = threadIdx.x;
    int c0 = b * BKT_NODES;
    int nb = NNODES - c0; if (nb > BKT_NODES) nb = BKT_NODES;
    int size = gcur[b]; if (size > BKT_CAP) size = BKT_CAP;
    int base = bktbase[b];
    const unsigned int* pp = pairbuf + (size_t)b * BKT_CAP;

    if (t < BKT_NODES) ncnt[t] = 0;
    __syncthreads();
    for (int k = t; k < size; k += 256)
        atomicAdd(&ncnt[pp[k] & 127u], 1);
    __syncthreads();
    int myv = (t < BKT_NODES) ? ncnt[t] : 0;
    if (t < BKT_NODES) nsc[t] = myv;
    __syncthreads();
    for (int off = 1; off < BKT_NODES; off <<= 1) {
        int u = 0;
        if (t < BKT_NODES && t >= off) u = nsc[t - off];
        __syncthreads();
        if (t < BKT_NODES) nsc[t] += u;
        __syncthreads();
    }
    if (t < BKT_NODES) {
        int excl = nsc[t] - myv;
        ncur[t] = excl;
        if (t < nb) {
            ptr[c0 + t] = base + excl;
            dinv[c0 + t] = rsqrtf((float)myv + 1.0f);  // +1 self-loop
        }
    }
    __syncthreads();
    for (int k = t; k < size; k += 256) {
        unsigned int pk = pp[k];
        int pos = atomicAdd(&ncur[pk & 127u], 1);
        seg[pos] = (int)(pk >> 7);  // LDS scatter (cheap), global stays coalesced
    }
    __syncthreads();
    for (int k = t; k < size; k += 256) adj[base + k] = seg[k];
}

// ---- layer kernels ----

// g1 = fp16(dinv * (x @ W1)).
// Block = 256 thr / 4 waves; 64-node x-tile staged in LDS via coalesced float4.
// Wave w computes nodes [w*16, w*16+16), lane = hidden j.
#define TILE 64
#define NT 16
__global__ __launch_bounds__(256) void k_gemm1(const float* __restrict__ x,
                                               const float* __restrict__ W1,
                                               const float* __restrict__ dinv,
                                               __half* __restrict__ g1) {
    __shared__ float shx[TILE][IN_DIM];  // 32 KB
    int t = threadIdx.x;
    int nbase = blockIdx.x * TILE;

    const float4* xg = reinterpret_cast<const float4*>(x + (size_t)nbase * IN_DIM);
    float4* shx4 = reinterpret_cast<float4*>(&shx[0][0]);
    int lim = (NNODES - nbase) * (IN_DIM / 4);
    if (lim > TILE * (IN_DIM / 4)) lim = TILE * (IN_DIM / 4);
#pragma unroll
    for (int it = 0; it < 8; ++it) {
        int idx = t + it * 256;
        if (idx < lim) shx4[idx] = xg[idx];
    }
    __syncthreads();

    int w = t >> 6;
    int lane = t & 63;
    int n0 = w * NT;

    float acc[NT];
#pragma unroll
    for (int n = 0; n < NT; ++n) acc[n] = 0.0f;

    for (int kc = 0; kc < IN_DIM / 4; ++kc) {
        float w0 = W1[(kc * 4 + 0) * HID + lane];  // coalesced 256B, L1-hot
        float w1 = W1[(kc * 4 + 1) * HID + lane];
        float w2 = W1[(kc * 4 + 2) * HID + lane];
        float w3 = W1[(kc * 4 + 3) * HID + lane];
#pragma unroll
        for (int n = 0; n < NT; ++n) {
            float4 xv = *reinterpret_cast<const float4*>(&shx[n0 + n][kc * 4]);
            acc[n] = fmaf(xv.x, w0, acc[n]);
            acc[n] = fmaf(xv.y, w1, acc[n]);
            acc[n] = fmaf(xv.z, w2, acc[n]);
            acc[n] = fmaf(xv.w, w3, acc[n]);
        }
    }
#pragma unroll
    for (int n = 0; n < NT; ++n) {
        int node = nbase + n0 + n;
        if (node < NNODES)
            g1[(size_t)node * HID + lane] = __float2half(dinv[node] * acc[n]);
    }
}

// fused: h1 = relu(dinv*(g1[i]+sum_nbr g1)+b1) in LDS; g2 = fp16(dinv*(h1@W2)).
// one wave per node; neighbor loop unrolled x8; gathers are 2B/lane (128B/wave).
__global__ __launch_bounds__(256) void k_agg1g2(const __half* __restrict__ g1,
                                                const int* __restrict__ ptr,
                                                const int* __restrict__ adj,
                                                const float* __restrict__ dinv,
                                                const float* __restrict__ b1,
                                                const float* __restrict__ W2,
                                                __half* __restrict__ g2) {
    __shared__ float sh[4][HID];
    int t = blockIdx.x * blockDim.x + threadIdx.x;
    int i = t >> 6;
    if (i >= NNODES) return;
    int lane = threadIdx.x & 63;
    int w = threadIdx.x >> 6;

    float s = __half2float(g1[(size_t)i * HID + lane]);  // self loop
    int p0 = ptr[i], p1 = ptr[i + 1];
    int p = p0;
    for (; p + 8 <= p1; p += 8) {
        int n0 = adj[p],     n1 = adj[p + 1], n2 = adj[p + 2], n3 = adj[p + 3];
        int n4 = adj[p + 4], n5 = adj[p + 5], n6 = adj[p + 6], n7 = adj[p + 7];
        float v0 = __half2float(g1[(size_t)n0 * HID + lane]);
        float v1 = __half2float(g1[(size_t)n1 * HID + lane]);
        float v2 = __half2float(g1[(size_t)n2 * HID + lane]);
        float v3 = __half2float(g1[(size_t)n3 * HID + lane]);
        float v4 = __half2float(g1[(size_t)n4 * HID + lane]);
        float v5 = __half2float(g1[(size_t)n5 * HID + lane]);
        float v6 = __half2float(g1[(size_t)n6 * HID + lane]);
        float v7 = __half2float(g1[(size_t)n7 * HID + lane]);
        s += ((v0 + v1) + (v2 + v3)) + ((v4 + v5) + (v6 + v7));
    }
    for (; p < p1; ++p) s += __half2float(g1[(size_t)adj[p] * HID + lane]);

    float di = dinv[i];
    float h = fmaxf(fmaf(di, s, b1[lane]), 0.0f);
    sh[w][lane] = h;  // wave-synchronous, no barrier needed

    int j2 = lane & 31;
    int half = lane >> 5;
    float acc = 0.0f;
#pragma unroll
    for (int j = 0; j < 32; ++j) {
        int jj = half * 32 + j;
        acc = fmaf(sh[w][jj], W2[jj * OUTD + j2], acc);
    }
    acc += __shfl_xor(acc, 32);
    if (half == 0) g2[(size_t)i * OUTD + j2] = __float2half(di * acc);
}

// out = dinv * (g2[i] + sum_nbr g2[nbr]) + b2; half-wave per node, unrolled x8.
__global__ void k_agg2(const __half* __restrict__ g2, const int* __restrict__ ptr,
                       const int* __restrict__ adj, const float* __restrict__ dinv,
                       const float* __restrict__ b2, float* __restrict__ out) {
    int t = blockIdx.x * blockDim.x + threadIdx.x;
    int i = t >> 5;
    int j = t & 31;
    if (i >= NNODES) return;
    float s = __half2float(g2[(size_t)i * OUTD + j]);  // self loop
    int p0 = ptr[i], p1 = ptr[i + 1];
    int p = p0;
    for (; p + 8 <= p1; p += 8) {
        int n0 = adj[p],     n1 = adj[p + 1], n2 = adj[p + 2], n3 = adj[p + 3];
        int n4 = adj[p + 4], n5 = adj[p + 5], n6 = adj[p + 6], n7 = adj[p + 7];
        float v0 = __half2float(g2[(size_t)n0 * OUTD + j]);
        float v1 = __half2float(g2[(size_t)n1 * OUTD + j]);
        float v2 = __half2float(g2[(size_t)n2 * OUTD + j]);
        float v3 = __half2float(g2[(size_t)n3 * OUTD + j]);
        float v4 = __half2float(g2[(size_t)n4 * OUTD + j]);
        float v5 = __half2float(g2[(size_t)n5 * OUTD + j]);
        float v6 = __half2float(g2[(size_t)n6 * OUTD + j]);
        float v7 = __half2float(g2[(size_t)n7 * OUTD + j]);
        s += ((v0 + v1) + (v2 + v3)) + ((v4 + v5) + (v6 + v7));
    }
    for (; p < p1; ++p) s += __half2float(g2[(size_t)adj[p] * OUTD + j]);
    out[(size_t)i * OUTD + j] = fmaf(dinv[i], s, b2[j]);
}

extern "C" void kernel_launch(void* const* d_in, const int* in_sizes, int n_in,
                              void* d_out, int out_size, void* d_ws, size_t ws_size,
                              hipStream_t stream) {
    const float* x  = (const float*)d_in[0];
    const int*   ei = (const int*)d_in[1];   // [2, E]
    const float* W1 = (const float*)d_in[2];
    const float* b1 = (const float*)d_in[3];
    const float* W2 = (const float*)d_in[4];
    const float* b2 = (const float*)d_in[5];
    float* out = (float*)d_out;

    const int* row = ei;            // source
    const int* col = ei + NEDGES;   // target

    char* ws = (char*)d_ws;
    size_t off = 0;
    auto alloc = [&](size_t bytes) {
        void* p = ws + off;
        off = (off + bytes + 511) & ~(size_t)511;
        return p;
    };
    int*    gcur    = (int*)   alloc((size_t)NBUK * 4);
    int*    bktbase = (int*)   alloc((size_t)(NBUK + 1) * 4);
    int*    ptr     = (int*)   alloc((size_t)(NNODES + 1) * 4);
    float*  dinv    = (float*) alloc((size_t)NNODES * 4);
    int*    adj     = (int*)   alloc((size_t)NEDGES * 4);
    __half* g2      = (__half*)alloc((size_t)NNODES * OUTD * 2);
    // pairbuf (11.2MB) and g1 (12.8MB) share one region: pairbuf dead after k_pass2.
    size_t big = (size_t)NBUK * BKT_CAP * 4;
    size_t g1b = (size_t)NNODES * HID * 2;
    unsigned int* pairbuf = (unsigned int*)alloc(big > g1b ? big : g1b);
    __half* g1 = (__half*)pairbuf;

    const int B = 256;
    hipMemsetAsync(gcur, 0, (size_t)NBUK * 4, stream);
    k_pass1<<<P1_BLOCKS, 256, 0, stream>>>(row, col, gcur, pairbuf);
    k_bktscan<<<1, 1024, 0, stream>>>(gcur, bktbase, ptr);
    k_pass2<<<NBUK, 256, 0, stream>>>(pairbuf, gcur, bktbase, ptr, dinv, adj);

    {
        int nblk = (NNODES + TILE - 1) / TILE;  // 1563
        k_gemm1<<<nblk, 256, 0, stream>>>(x, W1, dinv, g1);
    }
    {
        long long tot = (long long)NNODES * HID;
        k_agg1g2<<<(int)((tot + B - 1) / B), B, 0, stream>>>(g1, ptr, adj, dinv, b1, W2, g2);
    }
    {
        long long tot = (long long)NNODES * OUTD;
        k_agg2<<<(int)((tot + B - 1) / B), B, 0, stream>>>(g2, ptr, adj, dinv, b2, out);
    }
}

// Round 10
// 295.942 us; speedup vs baseline: 1.2618x; 1.0156x over previous
//
#include <hip/hip_runtime.h>
#include <hip/hip_fp16.h>

// GCN: N=100000 nodes, E=1600000 edges, dims 128 -> 64 -> 32.
// CSR-by-destination via bucketed counting sort; gather-based aggregation.
// g1/g2 stored fp16. Gathers vectorized: 2 neighbor rows per load instr (agg1,
// lanes split 32/32), 4 rows per load (agg2, lanes split 16/16/16/16); all hot
// address math 32-bit. Accumulation fp32.

#define NNODES 100000
#define NEDGES 1600000
#define IN_DIM 128
#define HID 64
#define OUTD 32

#define BKT_NODES 128
#define NBUK 782                        // ceil(100000/128)
#define BKT_CAP 3584                    // slots/bucket; mean load 2048
#define P1_BLOCKS 256
#define P1_CHUNK (NEDGES / P1_BLOCKS)   // 6250 exactly

// ---- CSR build ----

__global__ __launch_bounds__(256) void k_pass1(const int* __restrict__ row,
                                               const int* __restrict__ col,
                                               int* __restrict__ gcur,
                                               unsigned int* __restrict__ pairbuf) {
    __shared__ int lcnt[NBUK];
    __shared__ int lbase[NBUK];
    int t = threadIdx.x;
    int e0 = blockIdx.x * P1_CHUNK;
    int e1 = e0 + P1_CHUNK;
    for (int j = t; j < NBUK; j += 256) lcnt[j] = 0;
    __syncthreads();
    for (int e = e0 + t; e < e1; e += 256)
        atomicAdd(&lcnt[col[e] >> 7], 1);
    __syncthreads();
    for (int j = t; j < NBUK; j += 256) {
        int n = lcnt[j];
        lbase[j] = (n > 0) ? atomicAdd(&gcur[j], n) : 0;
    }
    __syncthreads();
    for (int j = t; j < NBUK; j += 256) lcnt[j] = 0;
    __syncthreads();
    for (int e = e0 + t; e < e1; e += 256) {
        int c = col[e];
        unsigned int pk = ((unsigned int)row[e] << 7) | (unsigned int)(c & 127);
        int b = c >> 7;
        int pos = lbase[b] + atomicAdd(&lcnt[b], 1);
        if (pos < BKT_CAP) pairbuf[(size_t)b * BKT_CAP + pos] = pk;
    }
}

__global__ __launch_bounds__(1024) void k_bktscan(const int* __restrict__ gcur,
                                                  int* __restrict__ bktbase,
                                                  int* __restrict__ ptr) {
    __shared__ int s[1024];
    int t = threadIdx.x;
    int v = (t < NBUK) ? gcur[t] : 0;
    s[t] = v;
    __syncthreads();
    for (int off = 1; off < 1024; off <<= 1) {
        int u = (t >= off) ? s[t - off] : 0;
        __syncthreads();
        s[t] += u;
        __syncthreads();
    }
    if (t < NBUK) bktbase[t] = s[t] - v;  // exclusive
    if (t == 0) { bktbase[NBUK] = NEDGES; ptr[NNODES] = NEDGES; }
}

__global__ __launch_bounds__(256) void k_pass2(const unsigned int* __restrict__ pairbuf,
                                               const int* __restrict__ gcur,
                                               const int* __restrict__ bktbase,
                                               int* __restrict__ ptr,
                                               float* __restrict__ dinv,
                                               int* __restrict__ adj) {
    __shared__ int ncnt[BKT_NODES];
    __shared__ int nsc[BKT_NODES];
    __shared__ int ncur[BKT_NODES];
    __shared__ int seg[BKT_CAP];
    int b = blockIdx.x;
    int t = threadIdx.x;
    int c0 = b * BKT_NODES;
    int nb = NNODES - c0; if (nb > BKT_NODES) nb = BKT_NODES;
    int size = gcur[b]; if (size > BKT_CAP) size = BKT_CAP;
    int base = bktbase[b];
    const unsigned int* pp = pairbuf + (size_t)b * BKT_CAP;

    if (t < BKT_NODES) ncnt[t] = 0;
    __syncthreads();
    for (int k = t; k < size; k += 256)
        atomicAdd(&ncnt[pp[k] & 127u], 1);
    __syncthreads();
    int myv = (t < BKT_NODES) ? ncnt[t] : 0;
    if (t < BKT_NODES) nsc[t] = myv;
    __syncthreads();
    for (int off = 1; off < BKT_NODES; off <<= 1) {
        int u = 0;
        if (t < BKT_NODES && t >= off) u = nsc[t - off];
        __syncthreads();
        if (t < BKT_NODES) nsc[t] += u;
        __syncthreads();
    }
    if (t < BKT_NODES) {
        int excl = nsc[t] - myv;
        ncur[t] = excl;
        if (t < nb) {
            ptr[c0 + t] = base + excl;
            dinv[c0 + t] = rsqrtf((float)myv + 1.0f);  // +1 self-loop
        }
    }
    __syncthreads();
    for (int k = t; k < size; k += 256) {
        unsigned int pk = pp[k];
        int pos = atomicAdd(&ncur[pk & 127u], 1);
        seg[pos] = (int)(pk >> 7);  // LDS scatter (cheap), global stays coalesced
    }
    __syncthreads();
    for (int k = t; k < size; k += 256) adj[base + k] = seg[k];
}

// ---- layer kernels ----

// g1 = fp16(dinv * (x @ W1)).
// Block = 256 thr / 4 waves; 64-node x-tile staged in LDS via coalesced float4.
#define TILE 64
#define NT 16
__global__ __launch_bounds__(256) void k_gemm1(const float* __restrict__ x,
                                               const float* __restrict__ W1,
                                               const float* __restrict__ dinv,
                                               __half* __restrict__ g1) {
    __shared__ float shx[TILE][IN_DIM];  // 32 KB
    int t = threadIdx.x;
    int nbase = blockIdx.x * TILE;

    const float4* xg = reinterpret_cast<const float4*>(x + (size_t)nbase * IN_DIM);
    float4* shx4 = reinterpret_cast<float4*>(&shx[0][0]);
    int lim = (NNODES - nbase) * (IN_DIM / 4);
    if (lim > TILE * (IN_DIM / 4)) lim = TILE * (IN_DIM / 4);
#pragma unroll
    for (int it = 0; it < 8; ++it) {
        int idx = t + it * 256;
        if (idx < lim) shx4[idx] = xg[idx];
    }
    __syncthreads();

    int w = t >> 6;
    int lane = t & 63;
    int n0 = w * NT;

    float acc[NT];
#pragma unroll
    for (int n = 0; n < NT; ++n) acc[n] = 0.0f;

    for (int kc = 0; kc < IN_DIM / 4; ++kc) {
        float w0 = W1[(kc * 4 + 0) * HID + lane];  // coalesced 256B, L1-hot
        float w1 = W1[(kc * 4 + 1) * HID + lane];
        float w2 = W1[(kc * 4 + 2) * HID + lane];
        float w3 = W1[(kc * 4 + 3) * HID + lane];
#pragma unroll
        for (int n = 0; n < NT; ++n) {
            float4 xv = *reinterpret_cast<const float4*>(&shx[n0 + n][kc * 4]);
            acc[n] = fmaf(xv.x, w0, acc[n]);
            acc[n] = fmaf(xv.y, w1, acc[n]);
            acc[n] = fmaf(xv.z, w2, acc[n]);
            acc[n] = fmaf(xv.w, w3, acc[n]);
        }
    }
#pragma unroll
    for (int n = 0; n < NT; ++n) {
        int node = nbase + n0 + n;
        if (node < NNODES)
            g1[(unsigned)node * HID + lane] = __float2half(dinv[node] * acc[n]);
    }
}

// fused layer1-agg + layer2-gemm. One wave per dest node.
// Gather: lanes 0-31 read neighbor A's 32 half2s, lanes 32-63 neighbor B's
// -> 1 load instr per 2 edges; 32-bit address math; fp32 accum; shfl_xor(32)
// combine. Then h1 in LDS, matvec h1@W2 (lane-halves + shfl).
__global__ __launch_bounds__(256) void k_agg1g2(const __half2* __restrict__ g1,
                                                const int* __restrict__ ptr,
                                                const int* __restrict__ adj,
                                                const float* __restrict__ dinv,
                                                const float* __restrict__ b1,
                                                const float* __restrict__ W2,
                                                __half* __restrict__ g2) {
    __shared__ float sh[4][HID];
    int t = blockIdx.x * blockDim.x + threadIdx.x;
    int i = t >> 6;
    if (i >= NNODES) return;
    unsigned lane = threadIdx.x & 63;
    int w = threadIdx.x >> 6;
    unsigned hi = lane >> 5;   // which edge of the pair
    unsigned hl = lane & 31;   // half2 index in row (features 2hl, 2hl+1)

    float2 acc = make_float2(0.0f, 0.0f);
    if (hi == 0) {  // self loop counted once (lo half only)
        float2 f = __half22float2(g1[((unsigned)i << 5) + hl]);
        acc.x = f.x; acc.y = f.y;
    }
    int p0 = ptr[i], p1 = ptr[i + 1];
    int p = p0;
    for (; p + 8 <= p1; p += 8) {   // 8 edges: 4 adj loads + 4 gathers
        int n0 = adj[p + hi];
        int n1 = adj[p + 2 + hi];
        int n2 = adj[p + 4 + hi];
        int n3 = adj[p + 6 + hi];
        float2 f0 = __half22float2(g1[((unsigned)n0 << 5) + hl]);
        float2 f1 = __half22float2(g1[((unsigned)n1 << 5) + hl]);
        float2 f2 = __half22float2(g1[((unsigned)n2 << 5) + hl]);
        float2 f3 = __half22float2(g1[((unsigned)n3 << 5) + hl]);
        acc.x += (f0.x + f1.x) + (f2.x + f3.x);
        acc.y += (f0.y + f1.y) + (f2.y + f3.y);
    }
    for (; p + 2 <= p1; p += 2) {
        int n = adj[p + hi];
        float2 f = __half22float2(g1[((unsigned)n << 5) + hl]);
        acc.x += f.x; acc.y += f.y;
    }
    if (p < p1 && hi == 0) {  // odd last edge: lo half only
        int n = adj[p];
        float2 f = __half22float2(g1[((unsigned)n << 5) + hl]);
        acc.x += f.x; acc.y += f.y;
    }
    acc.x += __shfl_xor(acc.x, 32);
    acc.y += __shfl_xor(acc.y, 32);

    float di = dinv[i];
    if (hi == 0) {
        sh[w][2 * hl]     = fmaxf(fmaf(di, acc.x, b1[2 * hl]), 0.0f);
        sh[w][2 * hl + 1] = fmaxf(fmaf(di, acc.y, b1[2 * hl + 1]), 0.0f);
    }
    // same wave wrote sh -> no barrier needed (compiler inserts lgkmcnt wait)

    unsigned j2 = lane & 31;
    unsigned half = lane >> 5;
    float mv = 0.0f;
#pragma unroll
    for (int j = 0; j < 32; ++j) {
        unsigned jj = half * 32 + j;
        mv = fmaf(sh[w][jj], W2[jj * OUTD + j2], mv);
    }
    mv += __shfl_xor(mv, 32);
    if (half == 0) g2[((unsigned)i << 5) + j2] = __float2half(di * mv);
}

// out = dinv * (self + sum_nbr) g2 + b2. One wave per node.
// g2 row = 16 half2s; lane quarter q gathers edge p+q -> 4 edges per load.
__global__ __launch_bounds__(256) void k_agg2(const __half2* __restrict__ g2,
                                              const int* __restrict__ ptr,
                                              const int* __restrict__ adj,
                                              const float* __restrict__ dinv,
                                              const float* __restrict__ b2,
                                              float2* __restrict__ out) {
    int t = blockIdx.x * blockDim.x + threadIdx.x;
    int i = t >> 6;
    if (i >= NNODES) return;
    unsigned lane = threadIdx.x & 63;
    unsigned q  = lane >> 4;   // which edge of the quad
    unsigned hl = lane & 15;   // half2 index in row (features 2hl, 2hl+1)

    float2 acc = make_float2(0.0f, 0.0f);
    if (q == 0) {  // self loop once
        float2 f = __half22float2(g2[((unsigned)i << 4) + hl]);
        acc.x = f.x; acc.y = f.y;
    }
    int p0 = ptr[i], p1 = ptr[i + 1];
    int p = p0;
    for (; p + 8 <= p1; p += 8) {   // 8 edges: 2 adj loads + 2 gathers
        int n0 = adj[p + q];
        int n1 = adj[p + 4 + q];
        float2 f0 = __half22float2(g2[((unsigned)n0 << 4) + hl]);
        float2 f1 = __half22float2(g2[((unsigned)n1 << 4) + hl]);
        acc.x += f0.x + f1.x;
        acc.y += f0.y + f1.y;
    }
    for (; p + 4 <= p1; p += 4) {
        int n = adj[p + q];
        float2 f = __half22float2(g2[((unsigned)n << 4) + hl]);
        acc.x += f.x; acc.y += f.y;
    }
    int rem = p1 - p;               // 0..3
    if ((int)q < rem) {
        int n = adj[p + q];
        float2 f = __half22float2(g2[((unsigned)n << 4) + hl]);
        acc.x += f.x; acc.y += f.y;
    }
    acc.x += __shfl_xor(acc.x, 16);
    acc.y += __shfl_xor(acc.y, 16);
    acc.x += __shfl_xor(acc.x, 32);
    acc.y += __shfl_xor(acc.y, 32);

    if (q == 0) {
        float di = dinv[i];
        out[((unsigned)i << 4) + hl] =
            make_float2(fmaf(di, acc.x, b2[2 * hl]), fmaf(di, acc.y, b2[2 * hl + 1]));
    }
}

extern "C" void kernel_launch(void* const* d_in, const int* in_sizes, int n_in,
                              void* d_out, int out_size, void* d_ws, size_t ws_size,
                              hipStream_t stream) {
    const float* x  = (const float*)d_in[0];
    const int*   ei = (const int*)d_in[1];   // [2, E]
    const float* W1 = (const float*)d_in[2];
    const float* b1 = (const float*)d_in[3];
    const float* W2 = (const float*)d_in[4];
    const float* b2 = (const float*)d_in[5];
    float2* out = (float2*)d_out;

    const int* row = ei;            // source
    const int* col = ei + NEDGES;   // target

    char* ws = (char*)d_ws;
    size_t off = 0;
    auto alloc = [&](size_t bytes) {
        void* p = ws + off;
        off = (off + bytes + 511) & ~(size_t)511;
        return p;
    };
    int*    gcur    = (int*)   alloc((size_t)NBUK * 4);
    int*    bktbase = (int*)   alloc((size_t)(NBUK + 1) * 4);
    int*    ptr     = (int*)   alloc((size_t)(NNODES + 1) * 4);
    float*  dinv    = (float*) alloc((size_t)NNODES * 4);
    int*    adj     = (int*)   alloc((size_t)NEDGES * 4);
    __half* g2      = (__half*)alloc((size_t)NNODES * OUTD * 2);
    // pairbuf (11.2MB) and g1 (12.8MB) share one region: pairbuf dead after k_pass2.
    size_t big = (size_t)NBUK * BKT_CAP * 4;
    size_t g1b = (size_t)NNODES * HID * 2;
    unsigned int* pairbuf = (unsigned int*)alloc(big > g1b ? big : g1b);
    __half* g1 = (__half*)pairbuf;

    const int B = 256;
    hipMemsetAsync(gcur, 0, (size_t)NBUK * 4, stream);
    k_pass1<<<P1_BLOCKS, 256, 0, stream>>>(row, col, gcur, pairbuf);
    k_bktscan<<<1, 1024, 0, stream>>>(gcur, bktbase, ptr);
    k_pass2<<<NBUK, 256, 0, stream>>>(pairbuf, gcur, bktbase, ptr, dinv, adj);

    {
        int nblk = (NNODES + TILE - 1) / TILE;  // 1563
        k_gemm1<<<nblk, 256, 0, stream>>>(x, W1, dinv, g1);
    }
    {
        long long tot = (long long)NNODES * 64;
        k_agg1g2<<<(int)((tot + B - 1) / B), B, 0, stream>>>(
            (const __half2*)g1, ptr, adj, dinv, b1, W2, g2);
    }
    {
        long long tot = (long long)NNODES * 64;
        k_agg2<<<(int)((tot + B - 1) / B), B, 0, stream>>>(
            (const __half2*)g2, ptr, adj, dinv, b2, out);
    }
}